// Round 1
// baseline (219.104 us; speedup 1.0000x reference)
//
#include <hip/hip_runtime.h>
#include <cmath>

namespace {
constexpr int BN = 1024;
constexpr int NC = 96;
constexpr int MT = 256;
constexpr int UL = 40;
constexpr int LS = 81;     // 2*UL+1 states
constexpr int PAIRS = 41;  // pairs per row (lane i -> states 2i, 2i+1)
constexpr int ROWS = 128;  // rows published to LDS per chain (max row ever read = 127)

template <int CTRL>
__device__ __forceinline__ float dppf(float v) {
  return __builtin_bit_cast(
      float, __builtin_amdgcn_update_dpp(0, __builtin_bit_cast(int, v), CTRL,
                                         0xf, 0xf, true));
}
__device__ __forceinline__ float rl63(float x) {
  return __builtin_bit_cast(
      float, __builtin_amdgcn_readlane(__builtin_bit_cast(int, x), 63));
}
__device__ __forceinline__ float wave_sum(float x) {
  x += dppf<0x111>(x);
  x += dppf<0x112>(x);
  x += dppf<0x114>(x);
  x += dppf<0x118>(x);
  x += dppf<0x142>(x);
  x += dppf<0x143>(x);
  return rl63(x);
}
// lane i <- lane i-1 (lane 0 <- 0)
__device__ __forceinline__ float wave_shr1(float v) { return dppf<0x138>(v); }
__device__ __forceinline__ float fast_rcp(float x) {
  return __builtin_amdgcn_rcpf(x);
}
__device__ __forceinline__ unsigned packu(float a, float b) {
  unsigned ua = __builtin_bit_cast(unsigned, a) >> 16;
  unsigned ub = __builtin_bit_cast(unsigned, b) & 0xffff0000u;
  return ua | ub;
}
__device__ __forceinline__ float bf_lo(unsigned u) {
  return __builtin_bit_cast(float, u << 16);
}
__device__ __forceinline__ float bf_hi(unsigned u) {
  return __builtin_bit_cast(float, u & 0xffff0000u);
}

constexpr float FQ = 1e8f;      // nominal row scale (shock headroom)
constexpr float SEPS = 1e-30f;  // rcp-input floor (NaN-proof)

// Fused CTC: block = item, wave 0 = alpha chain, wave 1 = beta chain.
// Chains run UNNORMALIZED with deadbeat compensated rescale (as before).
// Each wave publishes rows 0..127 (normalized, bf16x2, reference-aligned:
// beta pair-reversed+shifted so column c == reference b[2c],b[2c+1]) to LDS.
// Loss terms lh_t = sum_s (a/p)~[t][s] * b~[T-1-t][s] are computed DURING the
// chains: with a barrier after each 8-row publish (second half only), wave A
// computes term t iff C(t) := t + 8*floor(t/8) >= T-8 (own row in regs, beta
// row T-1-t from LDS); wave B computes term t = T-1-k at its step k iff
// !C(t) (own row in regs, alpha row t from LDS; availability C(k) is implied
// because k0(t)+k0(T-1-t) >= T-15 forbids double failure). Exact partition of
// t in [0,T). Rows read from LDS are always <= 127. No HBM intermediates.
__global__ __launch_bounds__(128) void ctc_fused_kernel(
    const float* __restrict__ gout, const int* __restrict__ glabel,
    const int* __restrict__ gw, float* __restrict__ loss_out) {
  __shared__ unsigned srows[2][ROWS * PAIRS];  // 41984 B -> 3 blocks/CU
  __shared__ float spart[2];
  const int b = blockIdx.x;
  const int ph = threadIdx.x >> 6;  // 0 = alpha, 1 = beta
  const int i = threadIdx.x & 63;
  const float* P = gout + (size_t)b * (NC * MT);  // P[c*MT + t]
  const int* lab = glabel + b * UL;
  const int T = gw[b] >> 2;  // [128,256]

  const int s0 = 2 * i, s1 = s0 + 1;
  const float h0f = (i <= 40) ? 1.f : 0.f;
  const float h1f = (i <= 39) ? 1.f : 0.f;
  const int iw = (i <= 40) ? i : 40;
  const bool act = (i <= 40);

  const float* pB;
  const float* pL;
  float mskf;
  int col;  // reference-aligned LDS column owned/read by this lane
  if (ph == 0) {  // alpha
    const int li = (i < UL) ? lab[i] : 0;
    const int lm = (i >= 1 && i < UL) ? lab[i - 1] : 0;
    pB = P;
    pL = P + (size_t)li * MT;
    mskf = (i >= 1 && i <= 39 && li != lm) ? 1.f : 0.f;
    col = iw;  // straight
  } else {  // beta: class-flipped probs, reversed labels
    const int rli = (i < UL) ? lab[UL - 1 - i] : 0;
    const int rlm = (i >= 1 && i < UL) ? lab[UL - i] : 0;
    pB = P + (size_t)(NC - 1) * MT;
    pL = P + (size_t)(NC - 1 - rli) * MT;
    mskf = (i >= 1 && i <= 39 && rli != rlm) ? 1.f : 0.f;
    col = 40 - iw;  // pair-reversed -> reference orientation
  }
  unsigned* mrow = srows[ph];            // my publish region [row][pair]
  const unsigned* orow = srows[1 - ph];  // partner region

  // ---- prob pipeline: current block unpacked, next block in flight ----
  float pbv[8], plv[8];
  float4 LA = *(const float4*)(pB + 0), LB = *(const float4*)(pB + 4);
  float4 MA = *(const float4*)(pL + 0), MB = *(const float4*)(pL + 4);
  pbv[0] = LA.x; pbv[1] = LA.y; pbv[2] = LA.z; pbv[3] = LA.w;
  pbv[4] = LB.x; pbv[5] = LB.y; pbv[6] = LB.z; pbv[7] = LB.w;
  plv[0] = MA.x; plv[1] = MA.y; plv[2] = MA.z; plv[3] = MA.w;
  plv[4] = MB.x; plv[5] = MB.y; plv[6] = MB.z; plv[7] = MB.w;
  LA = *(const float4*)(pB + 8); LB = *(const float4*)(pB + 12);
  MA = *(const float4*)(pL + 8); MB = *(const float4*)(pL + 12);

  // ---- t = 0 ----
  float v0 = (i == 0) ? pbv[0] : 0.f;
  float v1 = (i == 0) ? plv[0] : 0.f;
  float ss = wave_sum(v0 + v1);
  float r0q = FQ * fast_rcp(fmaxf(ss, SEPS));
  float r1q = FQ * fast_rcp(fmaxf(ss * r0q, SEPS));
  float r2q = FQ * fast_rcp(fmaxf(ss * r0q * r1q, SEPS));

  float f0[8], f1[8], fs[8];  // 8-step row buffer + raw row sums
  fs[0] = ss;
  if (ph == 0) {
    f0[0] = (i == 0) ? 1.f : 0.f;  // x = a_raw/p at t=0
    f1[0] = f0[0];
  } else {
    f0[0] = v0;
    f1[0] = 0.f;  // overwritten by step k=1's pm1
  }
  float acc = 0.f;  // sum of log(lh_t) over terms this wave owns

#define CTC_STEP(T_, K_)                                              \
  {                                                                   \
    float pm1 = wave_shr1(v1);                                        \
    if (ph == 1 && (K_) >= 1) f1[(K_)-1] = pm1;                       \
    const float rh0 = r0q * h0f, rh1 = r0q * h1f;                     \
    float u0 = v0 + pm1;                                              \
    float u1 = (v0 + v1) + pm1 * mskf;                                \
    const int start_ = LS - 2 * (T - (T_));                           \
    if (s0 < start_) u0 = 0.f;                                        \
    if (s1 < start_) u1 = 0.f;                                        \
    const float x0 = u0 * rh0, x1 = u1 * rh1;                         \
    float n0 = x0 * pbv[(K_)];                                        \
    float n1 = x1 * plv[(K_)];                                        \
    float ssn = wave_sum(n0 + n1);                                    \
    float rn = FQ * fast_rcp(fmaxf(ssn, SEPS) * r1q * r2q);           \
    rn = fminf(fmaxf(rn, 1e-20f), 1e20f);                             \
    r0q = r1q; r1q = r2q; r2q = rn;                                   \
    v0 = n0; v1 = n1;                                                 \
    fs[(K_)] = ssn;                                                   \
    if (ph == 0) { f0[(K_)] = x0; f1[(K_)] = x1; }                    \
    else { f0[(K_)] = n0; }                                           \
  }

  // Publish 8 rows (normalized + packed) to LDS; rows >= 128 never read.
#define CTC_PUB(T0_)                                                  \
  {                                                                   \
    if (ph == 1) f1[7] = wave_shr1(v1);                               \
    if (act && (T0_) < ROWS) {                                        \
      _Pragma("unroll")                                               \
      for (int k = 0; k < 8; ++k) {                                   \
        float inv = fast_rcp(fmaxf(fs[k], SEPS));                     \
        mrow[((T0_) + k) * PAIRS + col] =                             \
            packu(f0[k] * inv, f1[k] * inv);                          \
      }                                                               \
    }                                                                 \
  }

  // Compute owned loss terms for this 8-step block (barrier condition and
  // ownership are wave-uniform: functions of t0, k, T only).
#define CTC_TERMS(T0_)                                                \
  if (2 * (T0_) >= T - 15) {                                          \
    __syncthreads();                                                  \
    _Pragma("unroll")                                                 \
    for (int kk = 0; kk < 8; ++kk) {                                  \
      const int k = (T0_) + kk;                                       \
      if (k < T) {                                                    \
        const int tb = T - 1 - k;                                     \
        const bool ck = (k + (T0_) >= T - 8);                         \
        const bool mine =                                             \
            (ph == 0) ? ck : (ck && (tb + (tb & ~7) < T - 8));        \
        if (mine) {                                                   \
          const unsigned av = orow[tb * PAIRS + col];                 \
          const float inv = fast_rcp(fmaxf(fs[kk], SEPS));            \
          const float pr =                                            \
              (bf_lo(av) * f0[kk] + bf_hi(av) * f1[kk]) * inv;        \
          const float d = wave_sum(pr);                               \
          acc += __logf(fmaxf(d, 1e-37f));                            \
        }                                                             \
      }                                                               \
    }                                                                 \
  }

  // ---- prologue: steps 1..7, publish rows 0..7 (no terms possible: T>=128) --
#pragma unroll
  for (int k = 1; k < 8; ++k) CTC_STEP(k, k);
  CTC_PUB(0);

  // ---- main: blocks of 8 steps ----
  for (int t0 = 8; t0 < T; t0 += 8) {
    pbv[0] = LA.x; pbv[1] = LA.y; pbv[2] = LA.z; pbv[3] = LA.w;
    pbv[4] = LB.x; pbv[5] = LB.y; pbv[6] = LB.z; pbv[7] = LB.w;
    plv[0] = MA.x; plv[1] = MA.y; plv[2] = MA.z; plv[3] = MA.w;
    plv[4] = MB.x; plv[5] = MB.y; plv[6] = MB.z; plv[7] = MB.w;
    int np = t0 + 8;
    if (np > 248) np = 248;
    LA = *(const float4*)(pB + np); LB = *(const float4*)(pB + np + 4);
    MA = *(const float4*)(pL + np); MB = *(const float4*)(pL + np + 4);
#pragma unroll
    for (int k = 0; k < 8; ++k) CTC_STEP(t0 + k, k);
    CTC_PUB(t0);
    CTC_TERMS(t0);
  }
#undef CTC_STEP
#undef CTC_PUB
#undef CTC_TERMS

  if (i == 0) spart[ph] = -acc;  // acc is wave-uniform (readlane broadcast)
  __syncthreads();
  if (threadIdx.x == 0) {
    float L = spart[0] + spart[1];
    loss_out[b] = fminf(fmaxf(L, -1e30f), 1e30f);  // fmin/fmax absorb NaN
  }
}

__global__ void reduce_kernel(const float* __restrict__ loss_in,
                              float* __restrict__ out) {
  __shared__ double sm[256];
  const int tid = threadIdx.x;
  double s = 0.0;
  for (int k = tid; k < BN; k += 256) s += (double)loss_in[k];
  sm[tid] = s;
  __syncthreads();
  for (int w = 128; w >= 1; w >>= 1) {
    if (tid < w) sm[tid] += sm[tid + w];
    __syncthreads();
  }
  if (tid == 0) out[0] = (float)sm[0];
}
}  // namespace

extern "C" void kernel_launch(void* const* d_in, const int* in_sizes, int n_in,
                              void* d_out, int out_size, void* d_ws, size_t ws_size,
                              hipStream_t stream) {
  const float* gout = (const float*)d_in[0];
  const int* glabel = (const int*)d_in[1];
  const int* gw = (const int*)d_in[2];
  float* loss = (float*)d_ws;  // BN floats (4 KB) — no other workspace needed
  ctc_fused_kernel<<<BN, 128, 0, stream>>>(gout, glabel, gw, loss);
  reduce_kernel<<<1, 256, 0, stream>>>(loss, (float*)d_out);
}